// Round 8
// baseline (10226.916 us; speedup 1.0000x reference)
//
#include <hip/hip_runtime.h>
#include <stdint.h>

#define NROWS 16384
#define NCODES 16384
#define DIM 256

#define BM 128
#define BN 128
#define BK 32
#define NSPLIT 8
#define CSPLIT (NCODES / NSPLIT)   // 2048 codes per split
#define JT_PER (CSPLIT / BN)       // 16 code tiles per split
#define NT (JT_PER * (DIM / BK))   // 128 staged tiles per block

typedef __attribute__((address_space(1))) const void gas_t;
typedef __attribute__((address_space(3))) void las_t;

// ---------------- which input is z? (z ~ N(0,1), emb ~ N(0,1)/16384) ----------------
__global__ __launch_bounds__(256)
void vq_which_kernel(const float* __restrict__ p0, const float* __restrict__ p1,
                     int* __restrict__ flag)
{
    __shared__ float red[256];
    const int tid = threadIdx.x;
    float s = 0.f;
    for (int t = tid; t < 4096; t += 256) s += fabsf(p0[t]) - fabsf(p1[t]);
    red[tid] = s;
    __syncthreads();
    for (int k = 128; k > 0; k >>= 1) {
        if (tid < k) red[tid] += red[tid + k];
        __syncthreads();
    }
    if (tid == 0) flag[0] = (red[0] >= 0.f) ? 0 : 1;   // 0: p0 is z
}

// numpy pairwise fp32 sum of squares of a 256-float row (exact numpy order).
__device__ __forceinline__ float np_pairwise_sumsq256(const float* __restrict__ a)
{
    float H[2];
    #pragma unroll
    for (int h = 0; h < 2; ++h) {
        const float* p = a + h * 128;
        float r[8];
        #pragma unroll
        for (int j = 0; j < 8; ++j) r[j] = __fmul_rn(p[j], p[j]);
        for (int i = 8; i < 128; i += 8) {
            #pragma unroll
            for (int j = 0; j < 8; ++j)
                r[j] = __fadd_rn(r[j], __fmul_rn(p[i + j], p[i + j]));
        }
        H[h] = __fadd_rn(__fadd_rn(__fadd_rn(r[0], r[1]), __fadd_rn(r[2], r[3])),
                         __fadd_rn(__fadd_rn(r[4], r[5]), __fadd_rn(r[6], r[7])));
    }
    return __fadd_rn(H[0], H[1]);
}

// ---------------- per-row ||z||^2 in exact numpy order ----------------
#define AR_ROWS 32
#define AR_STR 260
__global__ __launch_bounds__(256)
void vq_arow_kernel(const float* __restrict__ p0, const float* __restrict__ p1,
                    const int* __restrict__ flag, float* __restrict__ arow_g)
{
    const float* __restrict__ Z = (flag[0] == 0) ? p0 : p1;
    __shared__ float ls[AR_ROWS * AR_STR];
    const int tid = threadIdx.x;
    const int row0 = blockIdx.x * AR_ROWS;
    #pragma unroll
    for (int q = 0; q < 8; ++q) {
        int f4 = tid + 256 * q;
        int r = f4 >> 6;
        int c = (f4 & 63) << 2;
        *(float4*)&ls[r * AR_STR + c] =
            *(const float4*)&Z[(size_t)(row0 + r) * DIM + c];
    }
    __syncthreads();
    if (tid < AR_ROWS) arow_g[row0 + tid] = np_pairwise_sumsq256(&ls[tid * AR_STR]);
}

// ---------------- init merge keys ----------------
__global__ __launch_bounds__(256)
void vq_keys_init(unsigned long long* __restrict__ keys)
{
    int i = blockIdx.x * 256 + threadIdx.x;
    if (i < NROWS) keys[i] = 0xFFFFFFFFFFFFFFFFull;
}

// ---------------- argmin over codes, numpy-fp32-exact semantics ----------------
// Double-buffered LDS staged by global_load_lds (zero staging VGPRs).
// LDS linear 32-float rows; XOR word-swizzle (word ^= row&7) applied on the
// per-lane GLOBAL source and on the LDS read side (both-sides T2/m173 rule).
// __launch_bounds__(256,2) pins the VGPR cap at 256; ev loads split in two
// 4-wide groups to keep transient live ranges short (spill guard, rule #20).
// d = fl32(A_i - 2*G_ij), G = sequential fp32 FMA chain, k ascending
// (kb↑, w↑, x,y,z,w) — identical rounding to numpy fp32 BLAS.
__global__ __launch_bounds__(256, 2)
void vq_argmin_kernel(const float* __restrict__ p0, const float* __restrict__ p1,
                      const int* __restrict__ flag, const float* __restrict__ arow_g,
                      unsigned long long* __restrict__ keys)
{
    const float* __restrict__ Z = (flag[0] == 0) ? p0 : p1;
    const float* __restrict__ E = (flag[0] == 0) ? p1 : p0;

    __shared__ float zsb[2][BM * BK];   // 16 KB per buffer
    __shared__ float esb[2][BN * BK];
    __shared__ float arow_s[BM];

    const int tid = threadIdx.x;
    const int tx = tid & 15;     // code lane: codes tx + 16*j
    const int ty = tid >> 4;     // row lane:  rows  ty + 16*i
    const int wid = tid >> 6;
    const int lane = tid & 63;
    const int row0 = blockIdx.x * BM;
    const int c_base = blockIdx.y * CSPLIT;

    if (tid < BM) arow_s[tid] = arow_g[row0 + tid];

    // DMA source geometry: wave 'wid' fills chunks ch=wid*4+q (q=0..3); each
    // chunk = 8 rows x 32 floats = 1 KB, lane l -> row (l>>3), word (l&7)^(l>>3).
    const int fg = (lane & 7) ^ (lane >> 3);     // pre-swizzled source word
    int zlo[4], elo[4];
    #pragma unroll
    for (int q = 0; q < 4; ++q) {
        const int ch = (wid << 2) + q;
        const int r = ch * 8 + (lane >> 3);
        zlo[q] = (row0 + r) * DIM + fg * 4;
        elo[q] = r * DIM + fg * 4;
    }
    const int swz = (ty & 7) << 2;   // read-side XOR (row&7 == ty&7), in floats
    const int swe = (tx & 7) << 2;

#define VQ_STAGE(BB, TT)                                                      \
    do {                                                                      \
        const int jn_ = (TT) >> 3;                                            \
        const int kn_ = (TT) & 7;                                             \
        const float* zt_ = Z + kn_ * BK;                                      \
        const float* et_ = E + (size_t)(c_base + jn_ * BN) * DIM + kn_ * BK;  \
        _Pragma("unroll")                                                     \
        for (int q_ = 0; q_ < 4; ++q_) {                                      \
            const int ch_ = (wid << 2) + q_;                                  \
            __builtin_amdgcn_global_load_lds(                                 \
                (gas_t*)(zt_ + zlo[q_]), (las_t*)&zsb[BB][ch_ << 8], 16, 0, 0);\
            __builtin_amdgcn_global_load_lds(                                 \
                (gas_t*)(et_ + elo[q_]), (las_t*)&esb[BB][ch_ << 8], 16, 0, 0);\
        }                                                                     \
    } while (0)

#define VQ_COMPUTE(BB)                                                        \
    _Pragma("unroll")                                                         \
    for (int w_ = 0; w_ < 8; ++w_) {                                          \
        const int zo_ = ((w_ << 2) ^ swz);                                    \
        const int eo_ = ((w_ << 2) ^ swe);                                    \
        float4 zv[8];                                                         \
        _Pragma("unroll")                                                     \
        for (int i = 0; i < 8; ++i)                                           \
            zv[i] = *(const float4*)&zsb[BB][((ty + 16 * i) << 5) + zo_];     \
        _Pragma("unroll")                                                     \
        for (int jh = 0; jh < 2; ++jh) {                                      \
            float4 ev[4];                                                     \
            _Pragma("unroll")                                                 \
            for (int j = 0; j < 4; ++j)                                       \
                ev[j] = *(const float4*)&esb[BB][((tx + 16 * (jh * 4 + j)) << 5) + eo_]; \
            _Pragma("unroll")                                                 \
            for (int i = 0; i < 8; ++i)                                       \
                _Pragma("unroll")                                             \
                for (int j = 0; j < 4; ++j) {                                 \
                    acc[i][jh * 4 + j] = __fmaf_rn(zv[i].x, ev[j].x, acc[i][jh * 4 + j]); \
                    acc[i][jh * 4 + j] = __fmaf_rn(zv[i].y, ev[j].y, acc[i][jh * 4 + j]); \
                    acc[i][jh * 4 + j] = __fmaf_rn(zv[i].z, ev[j].z, acc[i][jh * 4 + j]); \
                    acc[i][jh * 4 + j] = __fmaf_rn(zv[i].w, ev[j].w, acc[i][jh * 4 + j]); \
                }                                                             \
        }                                                                     \
    }

    // prologue: DMA tile 0 into buf0
    VQ_STAGE(0, 0);
    __syncthreads();

    float arow_r[8];
    #pragma unroll
    for (int i = 0; i < 8; ++i) arow_r[i] = arow_s[ty + 16 * i];

    float bestV[8];
    int bestI[8];
    #pragma unroll
    for (int i = 0; i < 8; ++i) { bestV[i] = 3.4e38f; bestI[i] = 0; }

    for (int jt = 0; jt < JT_PER; ++jt) {
        const int c0 = c_base + jt * BN;
        float acc[8][8];
        #pragma unroll
        for (int i = 0; i < 8; ++i)
            #pragma unroll
            for (int j = 0; j < 8; ++j) acc[i][j] = 0.0f;

        for (int kb2 = 0; kb2 < 4; ++kb2) {
            const int t0 = jt * 8 + kb2 * 2;
            // step A: compute buf0, prefetch t0+1 -> buf1
            VQ_STAGE(1, t0 + 1);
            VQ_COMPUTE(0)
            __syncthreads();
            // step B: compute buf1, prefetch t0+2 -> buf0
            if (t0 + 2 < NT) VQ_STAGE(0, t0 + 2);
            VQ_COMPUTE(1)
            __syncthreads();
        }

        #pragma unroll
        for (int j = 0; j < 8; ++j) {
            int c = c0 + tx + 16 * j;
            #pragma unroll
            for (int i = 0; i < 8; ++i) {
                float dd = __fsub_rn(arow_r[i], __fmul_rn(2.0f, acc[i][j]));
                if (dd < bestV[i]) { bestV[i] = dd; bestI[i] = c; }  // strict <: lowest idx
            }
        }
    }

    // per-row reduction across the 16 tx groups (reuse zsb/esb)
    __syncthreads();
    float* rv = &zsb[0][0];          // [BM][16]
    int* ri = (int*)&esb[0][0];      // [BM][16]
    #pragma unroll
    for (int i = 0; i < 8; ++i) {
        int r = ty + 16 * i;
        rv[r * 16 + tx] = bestV[i];
        ri[r * 16 + tx] = bestI[i];
    }
    __syncthreads();
    if (tid < BM) {
        float bv = rv[tid * 16];
        int bi = ri[tid * 16];
        for (int t = 1; t < 16; ++t) {
            float v = rv[tid * 16 + t];
            int ix = ri[tid * 16 + t];
            if (v < bv || (v == bv && ix < bi)) { bv = v; bi = ix; }
        }
        unsigned long long key =
            ((unsigned long long)__float_as_uint(bv) << 16) | (unsigned int)bi;
        atomicMin(&keys[row0 + tid], key);
    }
}

// ---------------- gather z_q, loss partials, float indices ----------------
__global__ __launch_bounds__(256)
void vq_gather_kernel(const float* __restrict__ p0, const float* __restrict__ p1,
                      const int* __restrict__ flag,
                      const unsigned long long* __restrict__ keys,
                      float* __restrict__ out_zq, float* __restrict__ out_idx_f,
                      double* __restrict__ partials)
{
    const float* __restrict__ Z = (flag[0] == 0) ? p0 : p1;
    const float* __restrict__ E = (flag[0] == 0) ? p1 : p0;

    const int tid = threadIdx.x;
    const int row0 = blockIdx.x * 64;
    double lsum = 0.0;
    for (int r = 0; r < 64; ++r) {
        int row = row0 + r;
        int id = (int)(keys[row] & 0xFFFFull);   // broadcast
        float e = E[(size_t)id * DIM + tid];
        float z = Z[(size_t)row * DIM + tid];
        out_zq[(size_t)row * DIM + tid] = e;
        double d = (double)e - (double)z;
        lsum += d * d;
    }
    __shared__ double red[256];
    red[tid] = lsum;
    __syncthreads();
    for (int s = 128; s > 0; s >>= 1) {
        if (tid < s) red[tid] += red[tid + s];
        __syncthreads();
    }
    if (tid == 0) partials[blockIdx.x] = red[0];
    if (tid < 64) out_idx_f[row0 + tid] = (float)(keys[row0 + tid] & 0xFFFFull);
}

__global__ void vq_loss_final(const double* __restrict__ partials, float* __restrict__ out_loss)
{
    const int tid = threadIdx.x;
    __shared__ double red[256];
    red[tid] = partials[tid];
    __syncthreads();
    for (int s = 128; s > 0; s >>= 1) {
        if (tid < s) red[tid] += red[tid + s];
        __syncthreads();
    }
    if (tid == 0) {
        double m = red[0] / ((double)NROWS * (double)DIM);
        out_loss[0] = (float)(1.25 * m);   // beta*mean + mean, identical values
    }
}

extern "C" void kernel_launch(void* const* d_in, const int* in_sizes, int n_in,
                              void* d_out, int out_size, void* d_ws, size_t ws_size,
                              hipStream_t stream)
{
    const float* p0 = (const float*)d_in[0];
    const float* p1 = (const float*)d_in[1];
    float* out = (float*)d_out;
    float* out_zq   = out;                 // 16384*256
    float* out_loss = out + 4194304;       // 1
    float* out_idxf = out + 4194305;       // 16384

    // ws layout: keys u64[16384] | arow f32[16384] | partials f64[256] | flag int
    unsigned long long* keys = (unsigned long long*)d_ws;
    float*  arow     = (float*)((char*)d_ws + 131072);
    double* partials = (double*)((char*)d_ws + 131072 + 65536);
    int*    flag     = (int*)((char*)d_ws + 131072 + 65536 + 2048);

    vq_which_kernel <<<1, 256, 0, stream>>>(p0, p1, flag);
    vq_arow_kernel  <<<NROWS / AR_ROWS, 256, 0, stream>>>(p0, p1, flag, arow);
    vq_keys_init    <<<NROWS / 256, 256, 0, stream>>>(keys);
    {
        dim3 grid(NROWS / BM, NSPLIT);
        vq_argmin_kernel <<<grid, 256, 0, stream>>>(p0, p1, flag, arow, keys);
    }
    vq_gather_kernel <<<NROWS / 64, 256, 0, stream>>>(p0, p1, flag, keys, out_zq, out_idxf, partials);
    vq_loss_final    <<<1, 256, 0, stream>>>(partials, out_loss);
}

// Round 9
// 1678.401 us; speedup vs baseline: 6.0933x; 6.0933x over previous
//
#include <hip/hip_runtime.h>
#include <stdint.h>

#define NROWS 16384
#define NCODES 16384
#define DIM 256

#define BM 128
#define BN 128
#define BK 32
#define NSPLIT 8
#define CSPLIT (NCODES / NSPLIT)   // 2048 codes per split
#define JT_PER (CSPLIT / BN)       // 16 code tiles per split
#define NT (JT_PER * (DIM / BK))   // 128 staged tiles per block

typedef __attribute__((address_space(1))) const void gas_t;
typedef __attribute__((address_space(3))) void las_t;

// ---------------- which input is z? (z ~ N(0,1), emb ~ N(0,1)/16384) ----------------
__global__ __launch_bounds__(256)
void vq_which_kernel(const float* __restrict__ p0, const float* __restrict__ p1,
                     int* __restrict__ flag)
{
    __shared__ float red[256];
    const int tid = threadIdx.x;
    float s = 0.f;
    for (int t = tid; t < 4096; t += 256) s += fabsf(p0[t]) - fabsf(p1[t]);
    red[tid] = s;
    __syncthreads();
    for (int k = 128; k > 0; k >>= 1) {
        if (tid < k) red[tid] += red[tid + k];
        __syncthreads();
    }
    if (tid == 0) flag[0] = (red[0] >= 0.f) ? 0 : 1;   // 0: p0 is z
}

// numpy pairwise fp32 sum of squares of a 256-float row (exact numpy order).
__device__ __forceinline__ float np_pairwise_sumsq256(const float* __restrict__ a)
{
    float H[2];
    #pragma unroll
    for (int h = 0; h < 2; ++h) {
        const float* p = a + h * 128;
        float r[8];
        #pragma unroll
        for (int j = 0; j < 8; ++j) r[j] = __fmul_rn(p[j], p[j]);
        for (int i = 8; i < 128; i += 8) {
            #pragma unroll
            for (int j = 0; j < 8; ++j)
                r[j] = __fadd_rn(r[j], __fmul_rn(p[i + j], p[i + j]));
        }
        H[h] = __fadd_rn(__fadd_rn(__fadd_rn(r[0], r[1]), __fadd_rn(r[2], r[3])),
                         __fadd_rn(__fadd_rn(r[4], r[5]), __fadd_rn(r[6], r[7])));
    }
    return __fadd_rn(H[0], H[1]);
}

// ---------------- per-row ||z||^2 in exact numpy order ----------------
#define AR_ROWS 32
#define AR_STR 260
__global__ __launch_bounds__(256)
void vq_arow_kernel(const float* __restrict__ p0, const float* __restrict__ p1,
                    const int* __restrict__ flag, float* __restrict__ arow_g)
{
    const float* __restrict__ Z = (flag[0] == 0) ? p0 : p1;
    __shared__ float ls[AR_ROWS * AR_STR];
    const int tid = threadIdx.x;
    const int row0 = blockIdx.x * AR_ROWS;
    #pragma unroll
    for (int q = 0; q < 8; ++q) {
        int f4 = tid + 256 * q;
        int r = f4 >> 6;
        int c = (f4 & 63) << 2;
        *(float4*)&ls[r * AR_STR + c] =
            *(const float4*)&Z[(size_t)(row0 + r) * DIM + c];
    }
    __syncthreads();
    if (tid < AR_ROWS) arow_g[row0 + tid] = np_pairwise_sumsq256(&ls[tid * AR_STR]);
}

// ---------------- init merge keys ----------------
__global__ __launch_bounds__(256)
void vq_keys_init(unsigned long long* __restrict__ keys)
{
    int i = blockIdx.x * 256 + threadIdx.x;
    if (i < NROWS) keys[i] = 0xFFFFFFFFFFFFFFFFull;
}

// ---------------- argmin over codes, numpy-fp32-exact semantics ----------------
// Double-buffered LDS staged by global_load_lds (zero staging VGPRs).
// LDS linear 32-float rows; XOR word-swizzle (word ^= row&7) applied on the
// per-lane GLOBAL source and on the LDS read side (both-sides T2/m173 rule).
// SPILL GUARD (rounds 5-8 lesson): jt/kb2/w_ loops are `#pragma unroll 1` so
// hipcc cannot flatten the 128-phase pipeline into straight-line code and
// hoist loads across phases (that was inflating live ranges past 256 VGPRs);
// compute is outer-product-ordered (ev[8] per k-chunk, single zv) for a
// ~150-reg steady live set.
// d = fl32(A_i - 2*G_ij), G = sequential fp32 FMA chain, k ascending
// (kb↑, w↑, x,y,z,w) — identical rounding to numpy fp32 BLAS.
__global__ __launch_bounds__(256, 1)
void vq_argmin_kernel(const float* __restrict__ p0, const float* __restrict__ p1,
                      const int* __restrict__ flag, const float* __restrict__ arow_g,
                      unsigned long long* __restrict__ keys)
{
    const float* __restrict__ Z = (flag[0] == 0) ? p0 : p1;
    const float* __restrict__ E = (flag[0] == 0) ? p1 : p0;

    __shared__ float zsb[2][BM * BK];   // 16 KB per buffer
    __shared__ float esb[2][BN * BK];
    __shared__ float arow_s[BM];

    const int tid = threadIdx.x;
    const int tx = tid & 15;     // code lane: codes tx + 16*j
    const int ty = tid >> 4;     // row lane:  rows  ty + 16*i
    const int wid = tid >> 6;
    const int lane = tid & 63;
    const int row0 = blockIdx.x * BM;
    const int c_base = blockIdx.y * CSPLIT;

    if (tid < BM) arow_s[tid] = arow_g[row0 + tid];

    // DMA source geometry: wave 'wid' fills chunks ch=wid*4+q (q=0..3); each
    // chunk = 8 rows x 32 floats = 1 KB, lane l -> row (l>>3), word (l&7)^(l>>3).
    const int fg = (lane & 7) ^ (lane >> 3);     // pre-swizzled source word
    int zlo[4], elo[4];
    #pragma unroll
    for (int q = 0; q < 4; ++q) {
        const int ch = (wid << 2) + q;
        const int r = ch * 8 + (lane >> 3);
        zlo[q] = (row0 + r) * DIM + fg * 4;
        elo[q] = r * DIM + fg * 4;
    }
    const int swz = (ty & 7) << 2;   // read-side XOR (row&7 == ty&7), in floats
    const int swe = (tx & 7) << 2;

#define VQ_STAGE(BB, TT)                                                      \
    do {                                                                      \
        const int jn_ = (TT) >> 3;                                            \
        const int kn_ = (TT) & 7;                                             \
        const float* zt_ = Z + kn_ * BK;                                      \
        const float* et_ = E + (size_t)(c_base + jn_ * BN) * DIM + kn_ * BK;  \
        _Pragma("unroll")                                                     \
        for (int q_ = 0; q_ < 4; ++q_) {                                      \
            const int ch_ = (wid << 2) + q_;                                  \
            __builtin_amdgcn_global_load_lds(                                 \
                (gas_t*)(zt_ + zlo[q_]), (las_t*)&zsb[BB][ch_ << 8], 16, 0, 0);\
            __builtin_amdgcn_global_load_lds(                                 \
                (gas_t*)(et_ + elo[q_]), (las_t*)&esb[BB][ch_ << 8], 16, 0, 0);\
        }                                                                     \
    } while (0)

#define VQ_COMPUTE(BB)                                                        \
    _Pragma("unroll 1")                                                       \
    for (int w_ = 0; w_ < 8; ++w_) {                                          \
        const int zo_ = ((w_ << 2) ^ swz);                                    \
        const int eo_ = ((w_ << 2) ^ swe);                                    \
        float4 ev[8];                                                         \
        _Pragma("unroll")                                                     \
        for (int j = 0; j < 8; ++j)                                           \
            ev[j] = *(const float4*)&esb[BB][((tx + 16 * j) << 5) + eo_];     \
        _Pragma("unroll")                                                     \
        for (int i = 0; i < 8; ++i) {                                         \
            float4 zv = *(const float4*)&zsb[BB][((ty + 16 * i) << 5) + zo_]; \
            _Pragma("unroll")                                                 \
            for (int j = 0; j < 8; ++j) {                                     \
                acc[i][j] = __fmaf_rn(zv.x, ev[j].x, acc[i][j]);              \
                acc[i][j] = __fmaf_rn(zv.y, ev[j].y, acc[i][j]);              \
                acc[i][j] = __fmaf_rn(zv.z, ev[j].z, acc[i][j]);              \
                acc[i][j] = __fmaf_rn(zv.w, ev[j].w, acc[i][j]);              \
            }                                                                 \
        }                                                                     \
    }

    // prologue: DMA tile 0 into buf0
    VQ_STAGE(0, 0);
    __syncthreads();

    float arow_r[8];
    #pragma unroll
    for (int i = 0; i < 8; ++i) arow_r[i] = arow_s[ty + 16 * i];

    float bestV[8];
    int bestI[8];
    #pragma unroll
    for (int i = 0; i < 8; ++i) { bestV[i] = 3.4e38f; bestI[i] = 0; }

    #pragma unroll 1
    for (int jt = 0; jt < JT_PER; ++jt) {
        const int c0 = c_base + jt * BN;
        float acc[8][8];
        #pragma unroll
        for (int i = 0; i < 8; ++i)
            #pragma unroll
            for (int j = 0; j < 8; ++j) acc[i][j] = 0.0f;

        #pragma unroll 1
        for (int kb2 = 0; kb2 < 4; ++kb2) {
            const int t0 = jt * 8 + kb2 * 2;
            // step A: compute buf0, prefetch t0+1 -> buf1
            VQ_STAGE(1, t0 + 1);
            VQ_COMPUTE(0)
            __syncthreads();
            // step B: compute buf1, prefetch t0+2 -> buf0
            if (t0 + 2 < NT) VQ_STAGE(0, t0 + 2);
            VQ_COMPUTE(1)
            __syncthreads();
        }

        #pragma unroll
        for (int j = 0; j < 8; ++j) {
            int c = c0 + tx + 16 * j;
            #pragma unroll
            for (int i = 0; i < 8; ++i) {
                float dd = __fsub_rn(arow_r[i], __fmul_rn(2.0f, acc[i][j]));
                if (dd < bestV[i]) { bestV[i] = dd; bestI[i] = c; }  // strict <: lowest idx
            }
        }
    }

    // per-row reduction across the 16 tx groups (reuse zsb/esb)
    __syncthreads();
    float* rv = &zsb[0][0];          // [BM][16]
    int* ri = (int*)&esb[0][0];      // [BM][16]
    #pragma unroll
    for (int i = 0; i < 8; ++i) {
        int r = ty + 16 * i;
        rv[r * 16 + tx] = bestV[i];
        ri[r * 16 + tx] = bestI[i];
    }
    __syncthreads();
    if (tid < BM) {
        float bv = rv[tid * 16];
        int bi = ri[tid * 16];
        for (int t = 1; t < 16; ++t) {
            float v = rv[tid * 16 + t];
            int ix = ri[tid * 16 + t];
            if (v < bv || (v == bv && ix < bi)) { bv = v; bi = ix; }
        }
        unsigned long long key =
            ((unsigned long long)__float_as_uint(bv) << 16) | (unsigned int)bi;
        atomicMin(&keys[row0 + tid], key);
    }
}

// ---------------- gather z_q, loss partials, float indices ----------------
__global__ __launch_bounds__(256)
void vq_gather_kernel(const float* __restrict__ p0, const float* __restrict__ p1,
                      const int* __restrict__ flag,
                      const unsigned long long* __restrict__ keys,
                      float* __restrict__ out_zq, float* __restrict__ out_idx_f,
                      double* __restrict__ partials)
{
    const float* __restrict__ Z = (flag[0] == 0) ? p0 : p1;
    const float* __restrict__ E = (flag[0] == 0) ? p1 : p0;

    const int tid = threadIdx.x;
    const int row0 = blockIdx.x * 64;
    double lsum = 0.0;
    for (int r = 0; r < 64; ++r) {
        int row = row0 + r;
        int id = (int)(keys[row] & 0xFFFFull);   // broadcast
        float e = E[(size_t)id * DIM + tid];
        float z = Z[(size_t)row * DIM + tid];
        out_zq[(size_t)row * DIM + tid] = e;
        double d = (double)e - (double)z;
        lsum += d * d;
    }
    __shared__ double red[256];
    red[tid] = lsum;
    __syncthreads();
    for (int s = 128; s > 0; s >>= 1) {
        if (tid < s) red[tid] += red[tid + s];
        __syncthreads();
    }
    if (tid == 0) partials[blockIdx.x] = red[0];
    if (tid < 64) out_idx_f[row0 + tid] = (float)(keys[row0 + tid] & 0xFFFFull);
}

__global__ void vq_loss_final(const double* __restrict__ partials, float* __restrict__ out_loss)
{
    const int tid = threadIdx.x;
    __shared__ double red[256];
    red[tid] = partials[tid];
    __syncthreads();
    for (int s = 128; s > 0; s >>= 1) {
        if (tid < s) red[tid] += red[tid + s];
        __syncthreads();
    }
    if (tid == 0) {
        double m = red[0] / ((double)NROWS * (double)DIM);
        out_loss[0] = (float)(1.25 * m);   // beta*mean + mean, identical values
    }
}

extern "C" void kernel_launch(void* const* d_in, const int* in_sizes, int n_in,
                              void* d_out, int out_size, void* d_ws, size_t ws_size,
                              hipStream_t stream)
{
    const float* p0 = (const float*)d_in[0];
    const float* p1 = (const float*)d_in[1];
    float* out = (float*)d_out;
    float* out_zq   = out;                 // 16384*256
    float* out_loss = out + 4194304;       // 1
    float* out_idxf = out + 4194305;       // 16384

    // ws layout: keys u64[16384] | arow f32[16384] | partials f64[256] | flag int
    unsigned long long* keys = (unsigned long long*)d_ws;
    float*  arow     = (float*)((char*)d_ws + 131072);
    double* partials = (double*)((char*)d_ws + 131072 + 65536);
    int*    flag     = (int*)((char*)d_ws + 131072 + 65536 + 2048);

    vq_which_kernel <<<1, 256, 0, stream>>>(p0, p1, flag);
    vq_arow_kernel  <<<NROWS / AR_ROWS, 256, 0, stream>>>(p0, p1, flag, arow);
    vq_keys_init    <<<NROWS / 256, 256, 0, stream>>>(keys);
    {
        dim3 grid(NROWS / BM, NSPLIT);
        vq_argmin_kernel <<<grid, 256, 0, stream>>>(p0, p1, flag, arow, keys);
    }
    vq_gather_kernel <<<NROWS / 64, 256, 0, stream>>>(p0, p1, flag, keys, out_zq, out_idxf, partials);
    vq_loss_final    <<<1, 256, 0, stream>>>(partials, out_loss);
}